// Round 2
// baseline (444.696 us; speedup 1.0000x reference)
//
#include <hip/hip_runtime.h>

// Problem constants
#define B_ 8
#define C_ 64
#define H_ 240
#define W_ 320
#define HW_ (H_ * W_)      // 76800
#define HW4_ (HW_ / 4)     // 19200
#define K_ 10
#define ALPHA_ 0.02f
#define DELTA_ 0.5f
#define MIN_WEIGHT_ 50.0f

// Fused persistent kernel: 512 blocks x 256 threads, 2 blocks/CU guaranteed
// by __launch_bounds__(256, 2)  (2 waves/EU * 4 EU / 4 waves-per-block = 2).
#define GRID_ 512
#define NCH 4              // channels per phase-A slab
#define ZSPLIT 4           // 16 cb * 8 b * 4 z = 512 slabs (one per block)
#define CHUNK_A (HW4_ / ZSPLIT)   // 4800 float4 per slab

// Workspace layout (floats):
//   [0, 5120)      sums[b*64+c][k]
//   [5120, 5200)   counts[b*10+k]
//   [5200, 5280)   S2[b*10+k]
//   [5280, 5360)   Nk[b*10+k]
//   [5360, 5364)   grid-barrier words (2 x {cnt, flag}, as unsigned)
//   [5376, 10496)  means[b*64+c][k]  (fully overwritten; not memset)

// ---------------------------------------------------------------------------
// Software grid barrier. Safe because all GRID_ blocks are co-resident.
// Agent-scope release/acquire emit the cross-XCD L2 writeback/invalidate
// (same lowering as cooperative-groups grid.sync).
// ---------------------------------------------------------------------------
__device__ __forceinline__ void grid_barrier(unsigned* cnt, unsigned* flag) {
  __syncthreads();                  // all waves of block drained (implicit vmcnt(0))
  if (threadIdx.x == 0) {
    __threadfence();                // release: publish this block's writes
    if (atomicAdd(cnt, 1u) == GRID_ - 1u) {
      __hip_atomic_store(flag, 1u, __ATOMIC_RELEASE, __HIP_MEMORY_SCOPE_AGENT);
    } else {
      while (__hip_atomic_load(flag, __ATOMIC_ACQUIRE,
                               __HIP_MEMORY_SCOPE_AGENT) == 0u)
        __builtin_amdgcn_s_sleep(8);
    }
  }
  __syncthreads();
  __threadfence();                  // acquire for all threads: invalidate stale caches
}

// ---------------------------------------------------------------------------
// Fused kernel: Phase A (sums/counts) -> barrier -> Phase B (means + intra
// S2/Nk) -> barrier -> Phase C (block 0: hinge + finalize).
// ---------------------------------------------------------------------------
__global__ __launch_bounds__(256, 2) void fused(
    const float* __restrict__ x, const int* __restrict__ cm,
    float* __restrict__ ws, float* __restrict__ out) {
  const int tid = threadIdx.x;
  const int bid = blockIdx.x;

  float* __restrict__ sums = ws;
  float* __restrict__ counts = ws + 5120;
  float* __restrict__ S2 = ws + 5200;
  float* __restrict__ Nk = ws + 5280;
  unsigned* bar = (unsigned*)(ws + 5360);
  float* __restrict__ means = ws + 5376;

  // ======================= Phase A: masked sums + counts ====================
  {
    const int cb = bid & 15;          // channel block 0..15
    const int b = (bid >> 4) & 7;
    const int z = bid >> 7;           // 0..3
    const int c0 = cb * NCH;
    const int lo = z * CHUNK_A;
    const int hi = lo + CHUNK_A;

    const float4* __restrict__ xp =
        (const float4*)(x + (size_t)(b * C_ + c0) * HW_);
    const int4* __restrict__ cp = (const int4*)(cm + (size_t)b * HW_);

    float acc[NCH][K_];
#pragma unroll
    for (int c = 0; c < NCH; ++c)
#pragma unroll
      for (int j = 0; j < K_; ++j) acc[c][j] = 0.f;
    float cnt[K_];
#pragma unroll
    for (int j = 0; j < K_; ++j) cnt[j] = 0.f;
    const bool do_cnt = (cb == 0);

    for (int i = lo + tid; i < hi; i += 256) {
      const int4 k4 = cp[i];
      float oh0[K_], oh1[K_], oh2[K_], oh3[K_];
#pragma unroll
      for (int j = 0; j < K_; ++j) {
        oh0[j] = (k4.x == j) ? 1.f : 0.f;
        oh1[j] = (k4.y == j) ? 1.f : 0.f;
        oh2[j] = (k4.z == j) ? 1.f : 0.f;
        oh3[j] = (k4.w == j) ? 1.f : 0.f;
      }
      if (do_cnt) {
#pragma unroll
        for (int j = 0; j < K_; ++j)
          cnt[j] += (oh0[j] + oh1[j]) + (oh2[j] + oh3[j]);
      }
#pragma unroll
      for (int c = 0; c < NCH; ++c) {
        const float4 v = xp[c * HW4_ + i];
#pragma unroll
        for (int j = 0; j < K_; ++j) {
          acc[c][j] += v.x * oh0[j];
          acc[c][j] += v.y * oh1[j];
          acc[c][j] += v.z * oh2[j];
          acc[c][j] += v.w * oh3[j];
        }
      }
    }

    // wave-level reduce, one atomic per wave per bin
#pragma unroll
    for (int c = 0; c < NCH; ++c) {
#pragma unroll
      for (int j = 0; j < K_; ++j) {
        float v = acc[c][j];
#pragma unroll
        for (int off = 32; off > 0; off >>= 1) v += __shfl_down(v, off, 64);
        if ((tid & 63) == 0)
          atomicAdd(&sums[(b * C_ + c0 + c) * K_ + j], v);
      }
    }
    if (do_cnt) {
#pragma unroll
      for (int j = 0; j < K_; ++j) {
        float v = cnt[j];
#pragma unroll
        for (int off = 32; off > 0; off >>= 1) v += __shfl_down(v, off, 64);
        if ((tid & 63) == 0) atomicAdd(&counts[b * K_ + j], v);
      }
    }
  }

  grid_barrier(&bar[0], &bar[1]);

  // ======================= Phase B: means + intra S2/Nk =====================
  __shared__ float mlds[C_ * K_];   // 640 floats, [c*10+k]
  __shared__ float nrm[K_];
  __shared__ float4 pd[256];
  __shared__ float s2b[K_];
  __shared__ float nkb[K_];
  {
    const int b = bid >> 6;           // 0..7
    const int cs = bid & 63;          // chunk stride offset
    const int lane_p = tid & 63;
    const int grp = tid >> 6;

    // means normalization, ONCE per block
    for (int i = tid; i < C_ * K_; i += 256) {
      const int k = i % K_;
      mlds[i] = sums[b * C_ * K_ + i] / (counts[b * K_ + k] + 1e-10f);
    }
    if (tid < K_) { s2b[tid] = 0.f; nkb[tid] = 0.f; }
    __syncthreads();
    if (tid < K_) {
      float n2 = 0.f;
#pragma unroll
      for (int c = 0; c < C_; ++c) {
        const float mm = mlds[c * K_ + tid];
        n2 += mm * mm;
      }
      nrm[tid] = 1.f / fmaxf(sqrtf(n2), 1e-12f);
    }
    __syncthreads();
    for (int i = tid; i < C_ * K_; i += 256) mlds[i] *= nrm[i % K_];
    __syncthreads();
    if (cs == 0) {
      for (int i = tid; i < C_ * K_; i += 256) means[b * C_ * K_ + i] = mlds[i];
    }

    const float4* __restrict__ xb = (const float4*)(x + (size_t)b * C_ * HW_);
    const int4* __restrict__ cmb = (const int4*)(cm + (size_t)b * HW_);
    const int c0 = grp * (C_ / 4);

    for (int chunk = cs; chunk < HW4_ / 64; chunk += 64) {
      const int p4 = chunk * 64 + lane_p;
      const int4 k4 = cmb[p4];
      const float* __restrict__ m0 = &mlds[c0 * K_ + k4.x];
      const float* __restrict__ m1 = &mlds[c0 * K_ + k4.y];
      const float* __restrict__ m2 = &mlds[c0 * K_ + k4.z];
      const float* __restrict__ m3 = &mlds[c0 * K_ + k4.w];

      float d0 = 0.f, d1 = 0.f, d2 = 0.f, d3 = 0.f;
#pragma unroll
      for (int cc = 0; cc < C_ / 4; ++cc) {
        const float4 v = xb[(c0 + cc) * HW4_ + p4];
        d0 += v.x * m0[cc * K_];
        d1 += v.y * m1[cc * K_];
        d2 += v.z * m2[cc * K_];
        d3 += v.w * m3[cc * K_];
      }
      pd[tid] = make_float4(d0, d1, d2, d3);
      __syncthreads();

      if (grp == 0) {
        float4 a = pd[lane_p];
        float4 bb = pd[lane_p + 64];
        float4 cc = pd[lane_p + 128];
        float4 dd = pd[lane_p + 192];
        const float i0 = 0.5f * (1.f - (a.x + bb.x + cc.x + dd.x));
        const float i1 = 0.5f * (1.f - (a.y + bb.y + cc.y + dd.y));
        const float i2 = 0.5f * (1.f - (a.z + bb.z + cc.z + dd.z));
        const float i3 = 0.5f * (1.f - (a.w + bb.w + cc.w + dd.w));

        atomicAdd(&s2b[k4.x], i0 * i0);
        atomicAdd(&s2b[k4.y], i1 * i1);
        atomicAdd(&s2b[k4.z], i2 * i2);
        atomicAdd(&s2b[k4.w], i3 * i3);
        atomicAdd(&nkb[k4.x], i0 > ALPHA_ ? 1.f : 0.f);
        atomicAdd(&nkb[k4.y], i1 > ALPHA_ ? 1.f : 0.f);
        atomicAdd(&nkb[k4.z], i2 > ALPHA_ ? 1.f : 0.f);
        atomicAdd(&nkb[k4.w], i3 > ALPHA_ ? 1.f : 0.f);
      }
      __syncthreads();   // pd/s2b consumed before next iteration overwrites
    }

    // one global flush per block (was one per chunk)
    if (tid < K_) {
      atomicAdd(&S2[b * K_ + tid], s2b[tid]);
      atomicAdd(&Nk[b * K_ + tid], nkb[tid]);
    }
  }

  grid_barrier(&bar[2], &bar[3]);

  // ======================= Phase C: hinge + finalize (block 0) ==============
  if (bid == 0) {
    float acc_h = 0.f;
    for (int t = tid; t < B_ * 45; t += 256) {
      const int b = t / 45;
      int idx = t % 45;
      int k = 0, l = 0;
      for (k = 0; k < K_; ++k) {
        const int row = K_ - 1 - k;
        if (idx < row) { l = k + 1 + idx; break; }
        idx -= row;
      }
      float g = 0.f;
      for (int c = 0; c < C_; ++c)
        g += means[(b * C_ + c) * K_ + k] * means[(b * C_ + c) * K_ + l];
      const float inter_d = 0.5f * (1.f - g);
      const float h = fmaxf(DELTA_ - inter_d, 0.f);
      acc_h += 2.f * h * h;  // (k,l) and (l,k)
    }

    float acc_i = 0.f, acc_n = 0.f;
    if (tid < B_ * K_) {
      const float nk = Nk[tid];
      acc_n = nk;
      const float w = fmaxf(nk, MIN_WEIGHT_) * (float)K_;
      acc_i = S2[tid] / w;
    }

    __shared__ float rh[256], ri[256], rn[256];
    rh[tid] = acc_h;
    ri[tid] = acc_i;
    rn[tid] = acc_n;
    __syncthreads();
    for (int s = 128; s > 0; s >>= 1) {
      if (tid < s) {
        rh[tid] += rh[tid + s];
        ri[tid] += ri[tid + s];
        rn[tid] += rn[tid + s];
      }
      __syncthreads();
    }
    if (tid == 0) {
      const float inter = rh[0] / (float)((K_ * (K_ - 1) / 2) * B_);
      float intra = ri[0] / (float)B_;
      if (!(rn[0] > 0.f)) intra = 0.f;
      out[0] = intra + inter;
      out[1] = intra;
      out[2] = inter;
    }
  }
}

extern "C" void kernel_launch(void* const* d_in, const int* in_sizes, int n_in,
                              void* d_out, int out_size, void* d_ws, size_t ws_size,
                              hipStream_t stream) {
  const float* x = (const float*)d_in[0];
  const int* cm = (const int*)d_in[1];
  float* ws = (float*)d_ws;

  // Zero accumulators + barrier words (ws is poisoned 0xAA before every call).
  hipMemsetAsync(d_ws, 0, 5376 * sizeof(float), stream);

  fused<<<GRID_, 256, 0, stream>>>(x, cm, ws, (float*)d_out);
}

// Round 3
// 340.974 us; speedup vs baseline: 1.3042x; 1.3042x over previous
//
#include <hip/hip_runtime.h>

// Problem constants
#define B_ 8
#define C_ 64
#define H_ 240
#define W_ 320
#define HW_ (H_ * W_)      // 76800
#define HW4_ (HW_ / 4)     // 19200
#define K_ 10
#define ALPHA_ 0.02f
#define DELTA_ 0.5f
#define MIN_WEIGHT_ 50.0f

#define NCH 4              // channels per k1 block (one-hot amortization)
#define CB_ (C_ / NCH)     // 16 channel-blocks
#define Z1 8               // pixel splits in k1 -> 16*8*8 = 1024 blocks
#define CHUNK1 (HW4_ / Z1) // 2400 float4 per slab

#define K3_BLOCKS (B_ * (HW4_ / 64))  // 2400

// Workspace float offsets (no memset needed; everything written before read):
//   SL_SUMS  [Z1][B*C*K]  partial sums per z-slice (pure writes in k1)
//   SL_CNT   [Z1][B*K]    partial counts per z-slice
//   OFF_S2   [B*K]        zeroed by k1 block 0, atomically accumulated in k3
//   OFF_NK   [B*K]        "
//   OFF_DONE [1]          "  (k3 completion counter, unsigned)
//   OFF_MEANS[B*C*K]      normalized means (written by k3 chunk-0 blocks)
#define SL_SUMS 0
#define SL_CNT  (Z1 * B_ * C_ * K_)        // 40960
#define OFF_S2  (SL_CNT + Z1 * B_ * K_)    // 41600
#define OFF_NK  (OFF_S2 + B_ * K_)         // 41680
#define OFF_DONE (OFF_NK + B_ * K_)        // 41760
#define OFF_MEANS 41792

// ---------------------------------------------------------------------------
// Kernel 1: masked channel sums + cluster counts -> private z-slices.
// No global atomics. Block (0,0,0) also zeroes S2/Nk/done (161 floats);
// stream order guarantees this lands before any k3 atomic.
// grid (CB_, B_, Z1), block 256.
// ---------------------------------------------------------------------------
__global__ __launch_bounds__(256) void k1_sums(
    const float* __restrict__ x, const int* __restrict__ cm,
    float* __restrict__ ws) {
  const int cb = blockIdx.x;       // channel block 0..15
  const int b = blockIdx.y;
  const int z = blockIdx.z;
  const int tid = threadIdx.x;
  const int c0 = cb * NCH;

  const int lo = z * CHUNK1;
  const int hi = lo + CHUNK1;

  const float4* __restrict__ xp =
      (const float4*)(x + (size_t)(b * C_ + c0) * HW_);
  const int4* __restrict__ cp = (const int4*)(cm + (size_t)b * HW_);

  float acc[NCH][K_];
#pragma unroll
  for (int c = 0; c < NCH; ++c)
#pragma unroll
    for (int j = 0; j < K_; ++j) acc[c][j] = 0.f;
  float cnt[K_];
#pragma unroll
  for (int j = 0; j < K_; ++j) cnt[j] = 0.f;
  const bool do_cnt = (cb == 0);

  for (int i = lo + tid; i < hi; i += 256) {
    const int4 k4 = cp[i];
    float oh0[K_], oh1[K_], oh2[K_], oh3[K_];
#pragma unroll
    for (int j = 0; j < K_; ++j) {
      oh0[j] = (k4.x == j) ? 1.f : 0.f;
      oh1[j] = (k4.y == j) ? 1.f : 0.f;
      oh2[j] = (k4.z == j) ? 1.f : 0.f;
      oh3[j] = (k4.w == j) ? 1.f : 0.f;
    }
    if (do_cnt) {
#pragma unroll
      for (int j = 0; j < K_; ++j)
        cnt[j] += (oh0[j] + oh1[j]) + (oh2[j] + oh3[j]);
    }
#pragma unroll
    for (int c = 0; c < NCH; ++c) {
      const float4 v = xp[c * HW4_ + i];
#pragma unroll
      for (int j = 0; j < K_; ++j) {
        acc[c][j] += v.x * oh0[j];
        acc[c][j] += v.y * oh1[j];
        acc[c][j] += v.z * oh2[j];
        acc[c][j] += v.w * oh3[j];
      }
    }
  }

  // wave-level shfl reduce -> LDS partials -> one plain store per bin
  __shared__ float partS[4][NCH * K_];
  __shared__ float partC[4][K_];
  const int w = tid >> 6;
#pragma unroll
  for (int c = 0; c < NCH; ++c) {
#pragma unroll
    for (int j = 0; j < K_; ++j) {
      float v = acc[c][j];
#pragma unroll
      for (int off = 32; off > 0; off >>= 1) v += __shfl_down(v, off, 64);
      if ((tid & 63) == 0) partS[w][c * K_ + j] = v;
    }
  }
  if (do_cnt) {
#pragma unroll
    for (int j = 0; j < K_; ++j) {
      float v = cnt[j];
#pragma unroll
      for (int off = 32; off > 0; off >>= 1) v += __shfl_down(v, off, 64);
      if ((tid & 63) == 0) partC[w][j] = v;
    }
  }
  __syncthreads();

  float* __restrict__ slice =
      ws + SL_SUMS + z * (B_ * C_ * K_) + (b * C_ + c0) * K_;
  for (int i = tid; i < NCH * K_; i += 256)
    slice[i] = (partS[0][i] + partS[1][i]) + (partS[2][i] + partS[3][i]);
  if (do_cnt && tid < K_) {
    ws[SL_CNT + z * (B_ * K_) + b * K_ + tid] =
        (partC[0][tid] + partC[1][tid]) + (partC[2][tid] + partC[3][tid]);
  }

  // zero the k3 accumulators (S2[80] + Nk[80] + done[1] = 161 contiguous)
  if (cb == 0 && b == 0 && z == 0 && tid < 161) ws[OFF_S2 + tid] = 0.f;
}

// ---------------------------------------------------------------------------
// Kernel 3: means (from z-slices) + per-pixel intra -> S2/Nk; the LAST block
// to finish runs the finalize phase (hinge + output) inline.
// grid (300, 8), block 256 = 64 pixel-lanes x 4 channel-groups.
// ---------------------------------------------------------------------------
__global__ __launch_bounds__(256) void k3_intra(
    const float* __restrict__ x, const int* __restrict__ cm,
    float* __restrict__ ws, float* __restrict__ out) {
  const int b = blockIdx.y;
  const int chunk = blockIdx.x;
  const int tid = threadIdx.x;
  const int lane_p = tid & 63;
  const int grp = tid >> 6;

  float* __restrict__ S2 = ws + OFF_S2;
  float* __restrict__ Nk = ws + OFF_NK;
  float* __restrict__ means = ws + OFF_MEANS;

  __shared__ float cntl[K_];
  __shared__ float mlds[C_ * K_];   // 640 floats, [c*10+k]
  __shared__ float nrm[K_];
  __shared__ float4 pd[256];
  __shared__ float s2b[K_];
  __shared__ float nkb[K_];

  // ---- counts then means from the 8 z-slices ----
  if (tid < K_) {
    float s = 0.f;
#pragma unroll
    for (int z = 0; z < Z1; ++z) s += ws[SL_CNT + z * (B_ * K_) + b * K_ + tid];
    cntl[tid] = s;
    s2b[tid] = 0.f;
    nkb[tid] = 0.f;
  }
  __syncthreads();
  for (int i = tid; i < C_ * K_; i += 256) {
    float s = 0.f;
#pragma unroll
    for (int z = 0; z < Z1; ++z)
      s += ws[SL_SUMS + z * (B_ * C_ * K_) + b * C_ * K_ + i];
    mlds[i] = s / (cntl[i % K_] + 1e-10f);
  }
  __syncthreads();
  if (tid < K_) {
    float n2 = 0.f;
#pragma unroll
    for (int c = 0; c < C_; ++c) {
      const float mm = mlds[c * K_ + tid];
      n2 += mm * mm;
    }
    nrm[tid] = 1.f / fmaxf(sqrtf(n2), 1e-12f);
  }
  __syncthreads();
  for (int i = tid; i < C_ * K_; i += 256) mlds[i] *= nrm[i % K_];
  __syncthreads();
  if (chunk == 0) {
    for (int i = tid; i < C_ * K_; i += 256) means[b * C_ * K_ + i] = mlds[i];
  }

  // ---- intra distances ----
  const int p4 = chunk * 64 + lane_p;
  const int4 k4 = ((const int4*)(cm + (size_t)b * HW_))[p4];
  const float4* __restrict__ xb = (const float4*)(x + (size_t)b * C_ * HW_);

  const int c0 = grp * (C_ / 4);
  const float* __restrict__ m0 = &mlds[c0 * K_ + k4.x];
  const float* __restrict__ m1 = &mlds[c0 * K_ + k4.y];
  const float* __restrict__ m2 = &mlds[c0 * K_ + k4.z];
  const float* __restrict__ m3 = &mlds[c0 * K_ + k4.w];

  float d0 = 0.f, d1 = 0.f, d2 = 0.f, d3 = 0.f;
#pragma unroll
  for (int cc = 0; cc < C_ / 4; ++cc) {
    const float4 v = xb[(c0 + cc) * HW4_ + p4];
    d0 += v.x * m0[cc * K_];
    d1 += v.y * m1[cc * K_];
    d2 += v.z * m2[cc * K_];
    d3 += v.w * m3[cc * K_];
  }
  pd[tid] = make_float4(d0, d1, d2, d3);
  __syncthreads();

  if (grp == 0) {
    float4 a = pd[lane_p];
    float4 bb = pd[lane_p + 64];
    float4 cc = pd[lane_p + 128];
    float4 dd = pd[lane_p + 192];
    const float i0 = 0.5f * (1.f - (a.x + bb.x + cc.x + dd.x));
    const float i1 = 0.5f * (1.f - (a.y + bb.y + cc.y + dd.y));
    const float i2 = 0.5f * (1.f - (a.z + bb.z + cc.z + dd.z));
    const float i3 = 0.5f * (1.f - (a.w + bb.w + cc.w + dd.w));

    atomicAdd(&s2b[k4.x], i0 * i0);
    atomicAdd(&s2b[k4.y], i1 * i1);
    atomicAdd(&s2b[k4.z], i2 * i2);
    atomicAdd(&s2b[k4.w], i3 * i3);
    atomicAdd(&nkb[k4.x], i0 > ALPHA_ ? 1.f : 0.f);
    atomicAdd(&nkb[k4.y], i1 > ALPHA_ ? 1.f : 0.f);
    atomicAdd(&nkb[k4.z], i2 > ALPHA_ ? 1.f : 0.f);
    atomicAdd(&nkb[k4.w], i3 > ALPHA_ ? 1.f : 0.f);
  }
  __syncthreads();

  if (tid < K_) {
    atomicAdd(&S2[b * K_ + tid], s2b[tid]);
    atomicAdd(&Nk[b * K_ + tid], nkb[tid]);
  }
  __syncthreads();   // S2/Nk atomics drained (vmcnt) before done-increment

  // ---- last block runs finalize ----
  __shared__ unsigned lastf;
  if (tid == 0) {
    __threadfence();  // release: means stores + atomics ordered before 'done'
    lastf = (atomicAdd((unsigned*)(ws + OFF_DONE), 1u) ==
             (unsigned)(K3_BLOCKS - 1))
                ? 1u
                : 0u;
  }
  __syncthreads();
  if (lastf == 0u) return;
  __threadfence();    // acquire: see all blocks' means/S2/Nk

  // ======================= finalize (former k4) =============================
  float acc_h = 0.f;
  for (int t = tid; t < B_ * 45; t += 256) {
    const int bb = t / 45;
    int idx = t % 45;
    int k = 0, l = 0;
    for (k = 0; k < K_; ++k) {
      const int row = K_ - 1 - k;
      if (idx < row) { l = k + 1 + idx; break; }
      idx -= row;
    }
    float g = 0.f;
    for (int c = 0; c < C_; ++c)
      g += means[(bb * C_ + c) * K_ + k] * means[(bb * C_ + c) * K_ + l];
    const float inter_d = 0.5f * (1.f - g);
    const float h = fmaxf(DELTA_ - inter_d, 0.f);
    acc_h += 2.f * h * h;  // (k,l) and (l,k)
  }

  float acc_i = 0.f, acc_n = 0.f;
  if (tid < B_ * K_) {
    const float nk = Nk[tid];
    acc_n = nk;
    const float w = fmaxf(nk, MIN_WEIGHT_) * (float)K_;
    acc_i = S2[tid] / w;
  }

  __shared__ float rh[256], ri[256], rn[256];
  rh[tid] = acc_h;
  ri[tid] = acc_i;
  rn[tid] = acc_n;
  __syncthreads();
  for (int s = 128; s > 0; s >>= 1) {
    if (tid < s) {
      rh[tid] += rh[tid + s];
      ri[tid] += ri[tid + s];
      rn[tid] += rn[tid + s];
    }
    __syncthreads();
  }
  if (tid == 0) {
    const float inter = rh[0] / (float)((K_ * (K_ - 1) / 2) * B_);
    float intra = ri[0] / (float)B_;
    if (!(rn[0] > 0.f)) intra = 0.f;
    out[0] = intra + inter;
    out[1] = intra;
    out[2] = inter;
  }
}

extern "C" void kernel_launch(void* const* d_in, const int* in_sizes, int n_in,
                              void* d_out, int out_size, void* d_ws, size_t ws_size,
                              hipStream_t stream) {
  const float* x = (const float*)d_in[0];
  const int* cm = (const int*)d_in[1];
  float* ws = (float*)d_ws;

  // No memset: slices/means are pure writes; S2/Nk/done zeroed inside k1.
  k1_sums<<<dim3(CB_, B_, Z1), 256, 0, stream>>>(x, cm, ws);
  k3_intra<<<dim3(HW4_ / 64, B_), 256, 0, stream>>>(x, cm, ws, (float*)d_out);
}